// Round 18
// baseline (808.144 us; speedup 1.0000x reference)
//
#include <hip/hip_runtime.h>
#include <cmath>

typedef __bf16 bf16;
typedef __attribute__((ext_vector_type(8))) __bf16 bf16x8;
typedef __attribute__((ext_vector_type(4))) __bf16 bf16x4;
typedef __attribute__((ext_vector_type(4))) float f32x4;

#define NB 2
#define NSEQ 2048
#define NDIM 512
#define NHEADS 8
#define DHEAD 64
#define NMEM 16
#define NJ 2064
#define NJP 2176        // 17*128
#define NFF 2048
#define NROWS (NB*NSEQ) // 4096
#define TBL 4111        // rel table width (rel+2047 in [0,4110])

enum { EPI_QKV = 0, EPI_GELUSPLIT = 1, EPI_RESID = 2 };

// XCD-aware chunked swizzle (requires n % 8 == 0)
__device__ __forceinline__ int xcd_swz(int bid, int n)
{
  const int cpx = n >> 3;
  return (bid & 7) * cpx + (bid >> 3);
}

// ---------------------------------------------------------------------------
// Split-precision GEMM with double-buffered global_load_lds prefetch.
// fp32 operands stored as bf16 (hi,lo). C = Ah*Bh + Al*Bh + Ah*Bl.
// ---------------------------------------------------------------------------
template<int BM, int BN, int WAVES_M, int WAVES_N, int EPI>
__global__ __launch_bounds__(256)
void gemm_split(const bf16* __restrict__ A, const bf16* __restrict__ B,
                void* __restrict__ Cv, const float* __restrict__ bias,
                void* __restrict__ Cv2, void* __restrict__ Cv3,
                int K, int lda, int ldb, int ldc, int loA, int loB)
{
  constexpr int BK = 32;
  constexpr int WM = BM / WAVES_M;
  constexpr int WN = BN / WAVES_N;
  constexpr int MF = WM / 16;
  constexpr int NF = WN / 16;
  constexpr int AI = (BM * BK * 2) / 4096;
  constexpr int BI = (BN * BK * 2) / 4096;
  __shared__ bf16 Ash[2][BM * BK];
  __shared__ bf16 Asl[2][BM * BK];
  __shared__ bf16 Bsh[2][BN * BK];
  __shared__ bf16 Bsl[2][BN * BK];

  const int bm0 = xcd_swz(blockIdx.x, gridDim.x) * BM;
  const int bn0 = blockIdx.y * BN;
  const int t = threadIdx.x;
  const int wave = t >> 6, lane = t & 63;
  const int wr = wave / WAVES_N, wc = wave % WAVES_N;
  const int sr = t >> 2, sc = t & 3;
  const int frow = lane & 15, fk = (lane >> 4) * 8;

  auto stage = [&](int buf, int k0) {
#pragma unroll
    for (int qi = 0; qi < AI; ++qi) {
      const long long ro = (long long)(bm0 + qi * 64 + sr) * lda + (k0 + sc * 8);
      __builtin_amdgcn_global_load_lds(
          (const __attribute__((address_space(1))) void*)(A + ro),
          (__attribute__((address_space(3))) void*)(&Ash[buf][qi * 2048 + wave * 512]), 16, 0, 0);
      __builtin_amdgcn_global_load_lds(
          (const __attribute__((address_space(1))) void*)(A + ro + loA),
          (__attribute__((address_space(3))) void*)(&Asl[buf][qi * 2048 + wave * 512]), 16, 0, 0);
    }
#pragma unroll
    for (int qi = 0; qi < BI; ++qi) {
      const long long ro = (long long)(bn0 + qi * 64 + sr) * ldb + (k0 + sc * 8);
      __builtin_amdgcn_global_load_lds(
          (const __attribute__((address_space(1))) void*)(B + ro),
          (__attribute__((address_space(3))) void*)(&Bsh[buf][qi * 2048 + wave * 512]), 16, 0, 0);
      __builtin_amdgcn_global_load_lds(
          (const __attribute__((address_space(1))) void*)(B + ro + loB),
          (__attribute__((address_space(3))) void*)(&Bsl[buf][qi * 2048 + wave * 512]), 16, 0, 0);
    }
  };

  f32x4 acc[MF][NF] = {};

  stage(0, 0);
  __syncthreads();
  int cur = 0;
  for (int k0 = 0; k0 < K; k0 += BK) {
    if (k0 + BK < K) stage(cur ^ 1, k0 + BK);
    bf16x8 afh[MF], afl[MF], bfh[NF], bfl[NF];
#pragma unroll
    for (int m = 0; m < MF; m++) {
      afh[m] = *(const bf16x8*)(&Ash[cur][(wr * WM + m * 16 + frow) * BK + fk]);
      afl[m] = *(const bf16x8*)(&Asl[cur][(wr * WM + m * 16 + frow) * BK + fk]);
    }
#pragma unroll
    for (int n = 0; n < NF; n++) {
      bfh[n] = *(const bf16x8*)(&Bsh[cur][(wc * WN + n * 16 + frow) * BK + fk]);
      bfl[n] = *(const bf16x8*)(&Bsl[cur][(wc * WN + n * 16 + frow) * BK + fk]);
    }
#pragma unroll
    for (int m = 0; m < MF; m++)
#pragma unroll
      for (int n = 0; n < NF; n++) {
        acc[m][n] = __builtin_amdgcn_mfma_f32_16x16x32_bf16(afh[m], bfh[n], acc[m][n], 0, 0, 0);
        acc[m][n] = __builtin_amdgcn_mfma_f32_16x16x32_bf16(afl[m], bfh[n], acc[m][n], 0, 0, 0);
        acc[m][n] = __builtin_amdgcn_mfma_f32_16x16x32_bf16(afh[m], bfl[n], acc[m][n], 0, 0, 0);
      }
    __syncthreads();
    cur ^= 1;
  }

#pragma unroll
  for (int m = 0; m < MF; m++) {
#pragma unroll
    for (int n = 0; n < NF; n++) {
      const int row0 = bm0 + wr * WM + m * 16 + (lane >> 4) * 4;
      const int col = bn0 + wc * WN + n * 16 + (lane & 15);
#pragma unroll
      for (int r = 0; r < 4; r++) {
        const float v = acc[m][n][r];
        const long long i = row0 + r;
        if (EPI == EPI_QKV) {
          const int bb = (int)(i >> 11);
          const int il = (int)(i & 2047);
          if (col < NDIM) {
            const float vq = v * 0.125f;
            bf16* base = (bf16*)Cv;
            const long long ih = i * (long long)(2 * NDIM) + col;
            bf16 h = (bf16)vq;
            base[ih] = h;
            base[ih + NDIM] = (bf16)(vq - (float)h);
          } else if (col < 2 * NDIM) {
            bf16* ks = (bf16*)Cv3;
            const long long ih = ((long long)bb * NJP + il + NMEM) * (long long)(2 * NDIM)
                               + (col - NDIM);
            bf16 h = (bf16)v;
            ks[ih] = h;
            ks[ih + NDIM] = (bf16)(v - (float)h);
          } else {
            ((float*)Cv2)[i * (long long)NDIM + (col - 2 * NDIM)] = v;
          }
        } else if (EPI == EPI_GELUSPLIT) {
          float u = v + bias[col];
          float gl = 0.5f * u * (1.0f + erff(u * 0.7071067811865476f));
          const long long ih = i * (long long)(2 * ldc) + col;
          bf16 h = (bf16)gl;
          ((bf16*)Cv)[ih] = h;
          ((bf16*)Cv)[ih + ldc] = (bf16)(gl - (float)h);
        } else {  // EPI_RESID
          float* xp = ((float*)Cv) + i * ldc + col;
          *xp = *xp + v + bias[col];
        }
      }
    }
  }
}

// ---------------------------------------------------------------------------
// Barrier-free direct-register S-GEMM: S_h(i,j) = q_h(i).k_h(j), K=64.
// grid (16, 17, 8); writes S[i][h][j]. XCD swizzle on i-tiles.
// ---------------------------------------------------------------------------
__global__ __launch_bounds__(256)
void s_gemm_direct(const bf16* __restrict__ Qs, const bf16* __restrict__ Ks,
                   float* __restrict__ S)
{
  const int h = blockIdx.z;
  const int bm0 = xcd_swz(blockIdx.x, gridDim.x) * 128;
  const int bn0 = blockIdx.y * 128;
  const int t = threadIdx.x;
  const int wave = t >> 6, lane = t & 63;
  const int wr = wave >> 1, wc = wave & 1;
  const int frow = lane & 15, fk = (lane >> 4) * 8;

  bf16x8 ah[4][2], al[4][2];
#pragma unroll
  for (int m = 0; m < 4; m++)
#pragma unroll
    for (int kk = 0; kk < 2; kk++) {
      const bf16* ap = Qs + (long long)(bm0 + wr * 64 + m * 16 + frow) * 1024
                     + h * 64 + kk * 32 + fk;
      ah[m][kk] = *(const bf16x8*)(ap);
      al[m][kk] = *(const bf16x8*)(ap + 512);
    }

  f32x4 acc[4][4] = {};
#pragma unroll
  for (int n = 0; n < 4; n++) {
    bf16x8 bh[2], bl[2];
#pragma unroll
    for (int kk = 0; kk < 2; kk++) {
      const bf16* bp = Ks + (long long)(bn0 + wc * 64 + n * 16 + frow) * 1024
                     + h * 64 + kk * 32 + fk;
      bh[kk] = *(const bf16x8*)(bp);
      bl[kk] = *(const bf16x8*)(bp + 512);
    }
#pragma unroll
    for (int m = 0; m < 4; m++)
#pragma unroll
      for (int kk = 0; kk < 2; kk++) {
        acc[m][n] = __builtin_amdgcn_mfma_f32_16x16x32_bf16(ah[m][kk], bh[kk], acc[m][n], 0, 0, 0);
        acc[m][n] = __builtin_amdgcn_mfma_f32_16x16x32_bf16(al[m][kk], bh[kk], acc[m][n], 0, 0, 0);
        acc[m][n] = __builtin_amdgcn_mfma_f32_16x16x32_bf16(ah[m][kk], bl[kk], acc[m][n], 0, 0, 0);
      }
  }

#pragma unroll
  for (int m = 0; m < 4; m++) {
#pragma unroll
    for (int n = 0; n < 4; n++) {
      const int row0 = bm0 + wr * 64 + m * 16 + (lane >> 4) * 4;
      const int col = bn0 + wc * 64 + n * 16 + (lane & 15);
#pragma unroll
      for (int r = 0; r < 4; r++)
        S[(long long)(row0 + r) * (NHEADS * NJP) + h * NJP + col] = acc[m][n][r];
    }
  }
}

// ---------------------------------------------------------------------------
// LayerNorm -> split bf16 (hi | lo), row stride 1024
// ---------------------------------------------------------------------------
__global__ __launch_bounds__(256)
void ln_kernel(const float* __restrict__ x, const float* __restrict__ g,
               const float* __restrict__ b, bf16* __restrict__ out)
{
  const int row = blockIdx.x * 4 + (threadIdx.x >> 6);
  const int lane = threadIdx.x & 63;
  const float* xr = x + (long long)row * NDIM;
  float4 a0 = ((const float4*)xr)[lane];
  float4 a1 = ((const float4*)xr)[lane + 64];
  float s = a0.x + a0.y + a0.z + a0.w + a1.x + a1.y + a1.z + a1.w;
  float ss = a0.x * a0.x + a0.y * a0.y + a0.z * a0.z + a0.w * a0.w
           + a1.x * a1.x + a1.y * a1.y + a1.z * a1.z + a1.w * a1.w;
#pragma unroll
  for (int d = 1; d < 64; d <<= 1) {
    s += __shfl_xor(s, d, 64);
    ss += __shfl_xor(ss, d, 64);
  }
  const float mean = s * (1.0f / NDIM);
  const float var = ss * (1.0f / NDIM) - mean * mean;
  const float rs = rsqrtf(var + 1e-5f);
  float4 g0 = ((const float4*)g)[lane], g1 = ((const float4*)g)[lane + 64];
  float4 b0 = ((const float4*)b)[lane], b1 = ((const float4*)b)[lane + 64];
  bf16* orow = out + (long long)row * (2 * NDIM);
  float y[8] = {
    (a0.x - mean) * rs * g0.x + b0.x, (a0.y - mean) * rs * g0.y + b0.y,
    (a0.z - mean) * rs * g0.z + b0.z, (a0.w - mean) * rs * g0.w + b0.w,
    (a1.x - mean) * rs * g1.x + b1.x, (a1.y - mean) * rs * g1.y + b1.y,
    (a1.z - mean) * rs * g1.z + b1.z, (a1.w - mean) * rs * g1.w + b1.w };
  bf16x4 h0, h1, l0, l1;
#pragma unroll
  for (int j = 0; j < 4; j++) {
    bf16 h = (bf16)y[j];      h0[j] = h;  l0[j] = (bf16)(y[j] - (float)h);
    bf16 h2 = (bf16)y[4 + j]; h1[j] = h2; l1[j] = (bf16)(y[4 + j] - (float)h2);
  }
  *(bf16x4*)(orow + lane * 4) = h0;
  *(bf16x4*)(orow + 256 + lane * 4) = h1;
  *(bf16x4*)(orow + 512 + lane * 4) = l0;
  *(bf16x4*)(orow + 768 + lane * 4) = l1;
}

// ---------------------------------------------------------------------------
// Ks edge rows: j<16 from mem_k (split), j in [2064,2176) zero. Both batches.
// ---------------------------------------------------------------------------
__global__ __launch_bounds__(256)
void ks_edges(const float* __restrict__ mem_k_l, bf16* __restrict__ Ks)
{
  const int idx = blockIdx.x * 256 + threadIdx.x;  // 2 * 128 * 512
  const int c = idx & 511;
  const int jj = (idx >> 9) & 127;
  const int bb = idx >> 16;
  const int j = (jj < NMEM) ? jj : (jj - NMEM + NJ);
  float kval = 0.f;
  if (jj < NMEM) kval = mem_k_l[((c >> 6) * NMEM + jj) * DHEAD + (c & 63)];
  bf16 hv = (bf16)kval;
  const long long ro = ((long long)bb * NJP + j) * (2 * NDIM) + c;
  Ks[ro] = hv;
  Ks[ro + NDIM] = (bf16)(kval - (float)hv);
}

// ---------------------------------------------------------------------------
// Fused talking-heads mix + bias + top-8 + softmax + sparse PV gather.
// t-group OUTER, h inner, __syncthreads per 2 t-groups (16KB lockstep window
// < 32KB L1 -> waves 2..8 L1-hit; half the barrier convoys of round-17).
// Selection via sort4 + bitonic top-8 merge (exact).
// ---------------------------------------------------------------------------
__global__ __launch_bounds__(512)
void mix_topk_gather(const float* __restrict__ S, const float* __restrict__ kvV,
                     const float* __restrict__ mem_v_l, const float* __restrict__ pp,
                     const float* __restrict__ table2, bf16* __restrict__ obufs,
                     int b)
{
  const int i = blockIdx.x;
  const int k = threadIdx.x >> 6;
  const int lane = threadIdx.x & 63;
  const float* srow = S + (long long)i * (NHEADS * NJP);

  float pk[8];
#pragma unroll
  for (int h = 0; h < 8; h++) pk[h] = pp[h * 8 + k];
  const float* t2k = table2 + k * TBL + (2047 - i);

  float v[34];
  float t8[8];
#pragma unroll
  for (int m = 0; m < 8; m++) t8[m] = -3.0e38f;

#define CXP(a, bq) { const float hi = fmaxf(a, bq); const float lo = fminf(a, bq); a = hi; bq = lo; }
#define CXT(a, bq) { const float hi = fmaxf(t8[a], t8[bq]); const float lo = fminf(t8[a], t8[bq]); t8[a] = hi; t8[bq] = lo; }

#pragma unroll
  for (int tp = 0; tp < 4; tp++) {
#pragma unroll
    for (int tq = 0; tq < 2; tq++) {
      const int t = tp * 2 + tq;
      const int j0 = 256 * t + 4 * lane;
      float4 a;
      a.x = t2k[j0];
      a.y = t2k[j0 + 1];
      a.z = t2k[j0 + 2];
      a.w = t2k[j0 + 3];
#pragma unroll
      for (int h = 0; h < 8; h++) {
        const float4 s4 = *(const float4*)(srow + h * NJP + j0);
        a.x = fmaf(s4.x, pk[h], a.x);
        a.y = fmaf(s4.y, pk[h], a.y);
        a.z = fmaf(s4.z, pk[h], a.z);
        a.w = fmaf(s4.w, pk[h], a.w);
      }
      v[4 * t + 0] = a.x; v[4 * t + 1] = a.y; v[4 * t + 2] = a.z; v[4 * t + 3] = a.w;
      // sort4 descending (5 CX)
      float s0 = a.x, s1 = a.y, s2 = a.z, s3 = a.w;
      CXP(s0, s1) CXP(s2, s3) CXP(s0, s2) CXP(s1, s3) CXP(s1, s2)
      // bitonic top-8 merge
      t8[4] = fmaxf(t8[4], s3);
      t8[5] = fmaxf(t8[5], s2);
      t8[6] = fmaxf(t8[6], s1);
      t8[7] = fmaxf(t8[7], s0);
      CXT(0, 4) CXT(1, 5) CXT(2, 6) CXT(3, 7)
      CXT(0, 2) CXT(1, 3) CXT(4, 6) CXT(5, 7)
      CXT(0, 1) CXT(2, 3) CXT(4, 5) CXT(6, 7)
    }
    __syncthreads();   // lockstep every 2 t-groups -> 16KB L1 window
  }
  // tail: 2 elems, sort2 + merge
  {
    const int j0 = 2048 + 2 * lane;
    const int jc = j0 < 2062 ? j0 : 2062;
    float ax = t2k[jc], ay = t2k[jc + 1];
#pragma unroll
    for (int h = 0; h < 8; h++) {
      const float2 s2v = *(const float2*)(srow + h * NJP + j0);
      ax = fmaf(s2v.x, pk[h], ax);
      ay = fmaf(s2v.y, pk[h], ay);
    }
    if (j0 >= NJ) ax = -1e30f;
    if (j0 + 1 >= NJ) ay = -1e30f;
    v[32] = ax; v[33] = ay;
    float s0 = ax, s1 = ay;
    CXP(s0, s1)
    t8[6] = fmaxf(t8[6], s1);
    t8[7] = fmaxf(t8[7], s0);
    CXT(0, 4) CXT(1, 5) CXT(2, 6) CXT(3, 7)
    CXT(0, 2) CXT(1, 3) CXT(4, 6) CXT(5, 7)
    CXT(0, 1) CXT(2, 3) CXT(4, 5) CXT(6, 7)
  }

  // values-only butterfly: global top-8 (sorted desc) in every lane
#pragma unroll
  for (int d = 1; d < 64; d <<= 1) {
    float o[8];
#pragma unroll
    for (int m = 0; m < 8; m++) o[m] = __shfl_xor(t8[m], d, 64);
#pragma unroll
    for (int m = 0; m < 4; m++) t8[m] = fmaxf(t8[m], o[7 - m]);
    t8[4] = fmaxf(t8[4], o[3]); t8[5] = fmaxf(t8[5], o[2]);
    t8[6] = fmaxf(t8[6], o[1]); t8[7] = fmaxf(t8[7], o[0]);
    CXT(0, 4) CXT(1, 5) CXT(2, 6) CXT(3, 7)
    CXT(0, 2) CXT(1, 3) CXT(4, 6) CXT(5, 7)
    CXT(0, 1) CXT(2, 3) CXT(4, 5) CXT(6, 7)
  }
#undef CXT
#undef CXP
  const float mx = t8[0];
  const float thr = t8[7];
  float denom = 0.f;
#pragma unroll
  for (int m = 0; m < 8; m++) denom += __expf(t8[m] - mx);
  const float inv = 1.0f / denom;

  float acc = 0.f;
#pragma unroll
  for (int t = 0; t < 8; t++) {
#pragma unroll
    for (int e = 0; e < 4; e++) {
      unsigned long long mball = __ballot(v[t * 4 + e] >= thr);
      while (mball) {
        const int l = __builtin_ctzll(mball);
        mball &= mball - 1;
        const int jj = 256 * t + 4 * l + e;
        const float sv = __shfl(v[t * 4 + e], l);
        const float w = __expf(sv - mx) * inv;
        const float vv = (jj < NMEM)
            ? mem_v_l[(k * NMEM + jj) * DHEAD + lane]
            : kvV[(long long)(b * NSEQ + (jj - NMEM)) * NDIM + k * DHEAD + lane];
        acc = fmaf(w, vv, acc);
      }
    }
  }
#pragma unroll
  for (int e = 0; e < 2; e++) {
    unsigned long long mball = __ballot(v[32 + e] >= thr);
    while (mball) {
      const int l = __builtin_ctzll(mball);
      mball &= mball - 1;
      const int jj = 2048 + 2 * l + e;
      const float sv = __shfl(v[32 + e], l);
      const float w = __expf(sv - mx) * inv;
      const float vv = (jj < NMEM)
          ? mem_v_l[(k * NMEM + jj) * DHEAD + lane]
          : kvV[(long long)(b * NSEQ + (jj - NMEM)) * NDIM + k * DHEAD + lane];
      acc = fmaf(w, vv, acc);
    }
  }

  const long long orow = (long long)(b * NSEQ + i) * (2 * NDIM) + k * DHEAD + lane;
  bf16 h = (bf16)acc;
  obufs[orow] = h;
  obufs[orow + NDIM] = (bf16)(acc - (float)h);
}

// ---------------------------------------------------------------------------
// fp32 weight (R x C row-major) -> split-transposed bf16 (C x 2R)
// ---------------------------------------------------------------------------
__global__ __launch_bounds__(256)
void transpose_split(const float* __restrict__ in, bf16* __restrict__ out,
                     int R, int C)
{
  const long long idx = (long long)blockIdx.x * 256 + threadIdx.x;
  if (idx >= (long long)R * C) return;
  const int r = (int)(idx / C);
  const int c = (int)(idx % C);
  float v = in[idx];
  bf16 h = (bf16)v;
  out[(long long)c * (2 * R) + r] = h;
  out[(long long)c * (2 * R) + R + r] = (bf16)(v - (float)h);
}

// ---------------------------------------------------------------------------
// T5 bias table, TRANSPOSED: table2[k][rel+2047]; exact boundaries via log2
// ---------------------------------------------------------------------------
__global__ __launch_bounds__(256)
void build_bias2(const float* __restrict__ rel_emb, float* __restrict__ table2)
{
  const int idx = blockIdx.x * 256 + threadIdx.x;
  if (idx >= 8 * TBL) return;
  const int k = idx / TBL;
  const int rel = (idx % TBL) - 2047;
  const int n = -rel;
  const int ret = (n < 0) ? 16 : 0;
  const int na = n < 0 ? -n : n;
  int bucket;
  if (na < 8) {
    bucket = ret + na;
  } else {
    int vl = 8 + (int)(log2((double)na * 0.125) * 2.0);
    vl = vl < 15 ? vl : 15;
    bucket = ret + vl;
  }
  table2[idx] = rel_emb[bucket * 8 + k];
}

// ---------------------------------------------------------------------------
extern "C" void kernel_launch(void* const* d_in, const int* in_sizes, int n_in,
                              void* d_out, int out_size, void* d_ws, size_t ws_size,
                              hipStream_t stream)
{
  const float* x_in    = (const float*)d_in[0];
  const float* ln1_g   = (const float*)d_in[1];
  const float* ln1_b   = (const float*)d_in[2];
  const float* Wq      = (const float*)d_in[3];
  const float* Wkv     = (const float*)d_in[4];
  const float* Wo      = (const float*)d_in[5];
  const float* bo      = (const float*)d_in[6];
  const float* pre_proj= (const float*)d_in[7];
  const float* mem_k   = (const float*)d_in[8];
  const float* mem_v   = (const float*)d_in[9];
  const float* ln2_g   = (const float*)d_in[10];
  const float* ln2_b   = (const float*)d_in[11];
  const float* W1      = (const float*)d_in[12];
  const float* b1      = (const float*)d_in[13];
  const float* W2      = (const float*)d_in[14];
  const float* b2      = (const float*)d_in[15];
  const float* rel_emb = (const float*)d_in[16];

  char* p = (char*)d_ws;
  auto alloc = [&](size_t bytes) -> char* {
    char* r = p;
    p += (bytes + 255) & ~(size_t)255;
    return r;
  };

  float* x    = (float*)alloc((size_t)NROWS * NDIM * 4);          // 8.4 MB
  char*  RA   = alloc((size_t)NROWS * 2 * NDIM * 2);              // 8.4 MB: hs | obufs
  bf16*  hs    = (bf16*)RA;
  bf16*  obufs = (bf16*)RA;
  char*  RB   = alloc((size_t)NROWS * 2 * NFF * 2);               // 33.6 MB: (Qs+Ks) | tbufs
  bf16*  Qs    = (bf16*)RB;
  bf16*  Ks    = (bf16*)(RB + (size_t)NROWS * 2 * NDIM * 2);
  bf16*  tbufs = (bf16*)RB;
  float* kvV  = (float*)alloc((size_t)NROWS * NDIM * 4);          // 8.4 MB (V only)
  float* S    = (float*)alloc((size_t)NSEQ * NHEADS * NJP * 4);   // 142.6 MB, [i][h][j]
  bf16*  WqkvT= (bf16*)alloc((size_t)2 * 3 * NDIM * 2 * NDIM * 2);
  bf16*  WoT  = (bf16*)alloc((size_t)2 * NDIM * 2 * NDIM * 2);
  bf16*  W1T  = (bf16*)alloc((size_t)2 * NFF * 2 * NDIM * 2);
  bf16*  W2T  = (bf16*)alloc((size_t)2 * NDIM * 2 * NFF * 2);
  float* table2= (float*)alloc((size_t)8 * TBL * 4);

  // ---- prep ----
  hipMemcpyAsync(x, x_in, (size_t)NROWS * NDIM * 4, hipMemcpyDeviceToDevice, stream);
  build_bias2<<<(8 * TBL + 255) / 256, 256, 0, stream>>>(rel_emb, table2);
  for (int l = 0; l < 2; l++) {
    bf16* WqkvT_l = WqkvT + (size_t)l * 3 * NDIM * 2 * NDIM;
    transpose_split<<<(NDIM * NDIM + 255) / 256, 256, 0, stream>>>(
        Wq + (size_t)l * NDIM * NDIM, WqkvT_l, NDIM, NDIM);
    transpose_split<<<(2 * NDIM * NDIM + 255) / 256, 256, 0, stream>>>(
        Wkv + (size_t)l * NDIM * 2 * NDIM, WqkvT_l + (size_t)NDIM * 2 * NDIM,
        NDIM, 2 * NDIM);
    transpose_split<<<(NDIM * NDIM + 255) / 256, 256, 0, stream>>>(
        Wo + (size_t)l * NDIM * NDIM, WoT + (size_t)l * NDIM * 2 * NDIM, NDIM, NDIM);
    transpose_split<<<(NDIM * NFF + 255) / 256, 256, 0, stream>>>(
        W1 + (size_t)l * NDIM * NFF, W1T + (size_t)l * NFF * 2 * NDIM, NDIM, NFF);
    transpose_split<<<(NFF * NDIM + 255) / 256, 256, 0, stream>>>(
        W2 + (size_t)l * NFF * NDIM, W2T + (size_t)l * NDIM * 2 * NFF, NFF, NDIM);
  }

  // ---- layers ----
  for (int l = 0; l < 2; l++) {
    const bf16* WqkvT_l = WqkvT + (size_t)l * 3 * NDIM * 2 * NDIM;
    const bf16* WoT_l  = WoT + (size_t)l * NDIM * 2 * NDIM;
    const bf16* W1T_l  = W1T + (size_t)l * NFF * 2 * NDIM;
    const bf16* W2T_l  = W2T + (size_t)l * NDIM * 2 * NFF;
    const float* mem_v_l = mem_v + (size_t)l * NHEADS * NMEM * DHEAD;

    ln_kernel<<<NROWS / 4, 256, 0, stream>>>(x, ln1_g + l * NDIM, ln1_b + l * NDIM, hs);
    // merged QKV: 128x64 tiles -> 32x24 = 768 blocks (3/CU)
    gemm_split<128, 64, 2, 2, EPI_QKV><<<dim3(NROWS / 128, 24), 256, 0, stream>>>(
        hs, WqkvT_l, Qs, nullptr, kvV, Ks, NDIM, 2 * NDIM, 2 * NDIM, 0, NDIM, NDIM);
    ks_edges<<<(2 * 128 * 512) / 256, 256, 0, stream>>>(
        mem_k + (size_t)l * NHEADS * NMEM * DHEAD, Ks);

    for (int b = 0; b < NB; b++) {
      s_gemm_direct<<<dim3(NSEQ / 128, NJP / 128, NHEADS), 256, 0, stream>>>(
          Qs + (long long)b * NSEQ * 1024, Ks + (long long)b * NJP * 1024, S);
      mix_topk_gather<<<NSEQ, 512, 0, stream>>>(
          S, kvV, mem_v_l, pre_proj + l * 64, table2, obufs, b);
    }

    // x += obuf @ Wo + bo  (64x64 tiles -> 512 blocks, 2/CU)
    gemm_split<64, 64, 2, 2, EPI_RESID><<<dim3(NROWS / 64, NDIM / 64), 256, 0, stream>>>(
        obufs, WoT_l, x, bo + l * NDIM, nullptr, nullptr,
        NDIM, 2 * NDIM, 2 * NDIM, NDIM, NDIM, NDIM);

    ln_kernel<<<NROWS / 4, 256, 0, stream>>>(x, ln2_g + l * NDIM, ln2_b + l * NDIM, hs);
    gemm_split<128, 128, 2, 2, EPI_GELUSPLIT><<<dim3(NROWS / 128, NFF / 128), 256, 0, stream>>>(
        hs, W1T_l, tbufs, b1 + l * NFF, nullptr, nullptr,
        NDIM, 2 * NDIM, 2 * NDIM, NFF, NDIM, NDIM);
    // x += gelu @ W2 + b2  (64x64 tiles -> 512 blocks, 2/CU)
    gemm_split<64, 64, 2, 2, EPI_RESID><<<dim3(NROWS / 64, NDIM / 64), 256, 0, stream>>>(
        tbufs, W2T_l, x, b2 + l * NDIM, nullptr, nullptr,
        NFF, 2 * NFF, 2 * NFF, NDIM, NFF, NFF);
  }

  hipMemcpyAsync(d_out, x, (size_t)out_size * 4, hipMemcpyDeviceToDevice, stream);
}

// Round 19
// 789.798 us; speedup vs baseline: 1.0232x; 1.0232x over previous
//
#include <hip/hip_runtime.h>
#include <cmath>

typedef __bf16 bf16;
typedef __attribute__((ext_vector_type(8))) __bf16 bf16x8;
typedef __attribute__((ext_vector_type(4))) __bf16 bf16x4;
typedef __attribute__((ext_vector_type(4))) float f32x4;

#define NB 2
#define NSEQ 2048
#define NDIM 512
#define NHEADS 8
#define DHEAD 64
#define NMEM 16
#define NJ 2064
#define NJP 2176        // 17*128
#define NFF 2048
#define NROWS (NB*NSEQ) // 4096
#define TBL 4111        // rel table width (rel+2047 in [0,4110])

enum { EPI_QKV = 0, EPI_GELUSPLIT = 1, EPI_RESID = 2 };

// XCD-aware chunked swizzle (requires n % 8 == 0)
__device__ __forceinline__ int xcd_swz(int bid, int n)
{
  const int cpx = n >> 3;
  return (bid & 7) * cpx + (bid >> 3);
}

// ---------------------------------------------------------------------------
// Split-precision GEMM with double-buffered global_load_lds prefetch.
// fp32 operands stored as bf16 (hi,lo). C = Ah*Bh + Al*Bh + Ah*Bl.
// ---------------------------------------------------------------------------
template<int BM, int BN, int WAVES_M, int WAVES_N, int EPI>
__global__ __launch_bounds__(256)
void gemm_split(const bf16* __restrict__ A, const bf16* __restrict__ B,
                void* __restrict__ Cv, const float* __restrict__ bias,
                void* __restrict__ Cv2, void* __restrict__ Cv3,
                int K, int lda, int ldb, int ldc, int loA, int loB)
{
  constexpr int BK = 32;
  constexpr int WM = BM / WAVES_M;
  constexpr int WN = BN / WAVES_N;
  constexpr int MF = WM / 16;
  constexpr int NF = WN / 16;
  constexpr int AI = (BM * BK * 2) / 4096;
  constexpr int BI = (BN * BK * 2) / 4096;
  __shared__ bf16 Ash[2][BM * BK];
  __shared__ bf16 Asl[2][BM * BK];
  __shared__ bf16 Bsh[2][BN * BK];
  __shared__ bf16 Bsl[2][BN * BK];

  const int bm0 = xcd_swz(blockIdx.x, gridDim.x) * BM;
  const int bn0 = blockIdx.y * BN;
  const int t = threadIdx.x;
  const int wave = t >> 6, lane = t & 63;
  const int wr = wave / WAVES_N, wc = wave % WAVES_N;
  const int sr = t >> 2, sc = t & 3;
  const int frow = lane & 15, fk = (lane >> 4) * 8;

  auto stage = [&](int buf, int k0) {
#pragma unroll
    for (int qi = 0; qi < AI; ++qi) {
      const long long ro = (long long)(bm0 + qi * 64 + sr) * lda + (k0 + sc * 8);
      __builtin_amdgcn_global_load_lds(
          (const __attribute__((address_space(1))) void*)(A + ro),
          (__attribute__((address_space(3))) void*)(&Ash[buf][qi * 2048 + wave * 512]), 16, 0, 0);
      __builtin_amdgcn_global_load_lds(
          (const __attribute__((address_space(1))) void*)(A + ro + loA),
          (__attribute__((address_space(3))) void*)(&Asl[buf][qi * 2048 + wave * 512]), 16, 0, 0);
    }
#pragma unroll
    for (int qi = 0; qi < BI; ++qi) {
      const long long ro = (long long)(bn0 + qi * 64 + sr) * ldb + (k0 + sc * 8);
      __builtin_amdgcn_global_load_lds(
          (const __attribute__((address_space(1))) void*)(B + ro),
          (__attribute__((address_space(3))) void*)(&Bsh[buf][qi * 2048 + wave * 512]), 16, 0, 0);
      __builtin_amdgcn_global_load_lds(
          (const __attribute__((address_space(1))) void*)(B + ro + loB),
          (__attribute__((address_space(3))) void*)(&Bsl[buf][qi * 2048 + wave * 512]), 16, 0, 0);
    }
  };

  f32x4 acc[MF][NF] = {};

  stage(0, 0);
  __syncthreads();
  int cur = 0;
  for (int k0 = 0; k0 < K; k0 += BK) {
    if (k0 + BK < K) stage(cur ^ 1, k0 + BK);
    bf16x8 afh[MF], afl[MF], bfh[NF], bfl[NF];
#pragma unroll
    for (int m = 0; m < MF; m++) {
      afh[m] = *(const bf16x8*)(&Ash[cur][(wr * WM + m * 16 + frow) * BK + fk]);
      afl[m] = *(const bf16x8*)(&Asl[cur][(wr * WM + m * 16 + frow) * BK + fk]);
    }
#pragma unroll
    for (int n = 0; n < NF; n++) {
      bfh[n] = *(const bf16x8*)(&Bsh[cur][(wc * WN + n * 16 + frow) * BK + fk]);
      bfl[n] = *(const bf16x8*)(&Bsl[cur][(wc * WN + n * 16 + frow) * BK + fk]);
    }
#pragma unroll
    for (int m = 0; m < MF; m++)
#pragma unroll
      for (int n = 0; n < NF; n++) {
        acc[m][n] = __builtin_amdgcn_mfma_f32_16x16x32_bf16(afh[m], bfh[n], acc[m][n], 0, 0, 0);
        acc[m][n] = __builtin_amdgcn_mfma_f32_16x16x32_bf16(afl[m], bfh[n], acc[m][n], 0, 0, 0);
        acc[m][n] = __builtin_amdgcn_mfma_f32_16x16x32_bf16(afh[m], bfl[n], acc[m][n], 0, 0, 0);
      }
    __syncthreads();
    cur ^= 1;
  }

#pragma unroll
  for (int m = 0; m < MF; m++) {
#pragma unroll
    for (int n = 0; n < NF; n++) {
      const int row0 = bm0 + wr * WM + m * 16 + (lane >> 4) * 4;
      const int col = bn0 + wc * WN + n * 16 + (lane & 15);
#pragma unroll
      for (int r = 0; r < 4; r++) {
        const float v = acc[m][n][r];
        const long long i = row0 + r;
        if (EPI == EPI_QKV) {
          const int bb = (int)(i >> 11);
          const int il = (int)(i & 2047);
          if (col < NDIM) {
            const float vq = v * 0.125f;
            bf16* base = (bf16*)Cv;
            const long long ih = i * (long long)(2 * NDIM) + col;
            bf16 h = (bf16)vq;
            base[ih] = h;
            base[ih + NDIM] = (bf16)(vq - (float)h);
          } else if (col < 2 * NDIM) {
            bf16* ks = (bf16*)Cv3;
            const long long ih = ((long long)bb * NJP + il + NMEM) * (long long)(2 * NDIM)
                               + (col - NDIM);
            bf16 h = (bf16)v;
            ks[ih] = h;
            ks[ih + NDIM] = (bf16)(v - (float)h);
          } else {
            ((float*)Cv2)[i * (long long)NDIM + (col - 2 * NDIM)] = v;
          }
        } else if (EPI == EPI_GELUSPLIT) {
          float u = v + bias[col];
          float gl = 0.5f * u * (1.0f + erff(u * 0.7071067811865476f));
          const long long ih = i * (long long)(2 * ldc) + col;
          bf16 h = (bf16)gl;
          ((bf16*)Cv)[ih] = h;
          ((bf16*)Cv)[ih + ldc] = (bf16)(gl - (float)h);
        } else {  // EPI_RESID
          float* xp = ((float*)Cv) + i * ldc + col;
          *xp = *xp + v + bias[col];
        }
      }
    }
  }
}

// ---------------------------------------------------------------------------
// Barrier-free direct-register S-GEMM: S_h(i,j) = q_h(i).k_h(j), K=64.
// grid (16, 17, 8); writes S[i][h][j]. XCD swizzle on i-tiles.
// ---------------------------------------------------------------------------
__global__ __launch_bounds__(256)
void s_gemm_direct(const bf16* __restrict__ Qs, const bf16* __restrict__ Ks,
                   float* __restrict__ S)
{
  const int h = blockIdx.z;
  const int bm0 = xcd_swz(blockIdx.x, gridDim.x) * 128;
  const int bn0 = blockIdx.y * 128;
  const int t = threadIdx.x;
  const int wave = t >> 6, lane = t & 63;
  const int wr = wave >> 1, wc = wave & 1;
  const int frow = lane & 15, fk = (lane >> 4) * 8;

  bf16x8 ah[4][2], al[4][2];
#pragma unroll
  for (int m = 0; m < 4; m++)
#pragma unroll
    for (int kk = 0; kk < 2; kk++) {
      const bf16* ap = Qs + (long long)(bm0 + wr * 64 + m * 16 + frow) * 1024
                     + h * 64 + kk * 32 + fk;
      ah[m][kk] = *(const bf16x8*)(ap);
      al[m][kk] = *(const bf16x8*)(ap + 512);
    }

  f32x4 acc[4][4] = {};
#pragma unroll
  for (int n = 0; n < 4; n++) {
    bf16x8 bh[2], bl[2];
#pragma unroll
    for (int kk = 0; kk < 2; kk++) {
      const bf16* bp = Ks + (long long)(bn0 + wc * 64 + n * 16 + frow) * 1024
                     + h * 64 + kk * 32 + fk;
      bh[kk] = *(const bf16x8*)(bp);
      bl[kk] = *(const bf16x8*)(bp + 512);
    }
#pragma unroll
    for (int m = 0; m < 4; m++)
#pragma unroll
      for (int kk = 0; kk < 2; kk++) {
        acc[m][n] = __builtin_amdgcn_mfma_f32_16x16x32_bf16(ah[m][kk], bh[kk], acc[m][n], 0, 0, 0);
        acc[m][n] = __builtin_amdgcn_mfma_f32_16x16x32_bf16(al[m][kk], bh[kk], acc[m][n], 0, 0, 0);
        acc[m][n] = __builtin_amdgcn_mfma_f32_16x16x32_bf16(ah[m][kk], bl[kk], acc[m][n], 0, 0, 0);
      }
  }

#pragma unroll
  for (int m = 0; m < 4; m++) {
#pragma unroll
    for (int n = 0; n < 4; n++) {
      const int row0 = bm0 + wr * 64 + m * 16 + (lane >> 4) * 4;
      const int col = bn0 + wc * 64 + n * 16 + (lane & 15);
#pragma unroll
      for (int r = 0; r < 4; r++)
        S[(long long)(row0 + r) * (NHEADS * NJP) + h * NJP + col] = acc[m][n][r];
    }
  }
}

// ---------------------------------------------------------------------------
// LayerNorm -> split bf16 (hi | lo), row stride 1024
// ---------------------------------------------------------------------------
__global__ __launch_bounds__(256)
void ln_kernel(const float* __restrict__ x, const float* __restrict__ g,
               const float* __restrict__ b, bf16* __restrict__ out)
{
  const int row = blockIdx.x * 4 + (threadIdx.x >> 6);
  const int lane = threadIdx.x & 63;
  const float* xr = x + (long long)row * NDIM;
  float4 a0 = ((const float4*)xr)[lane];
  float4 a1 = ((const float4*)xr)[lane + 64];
  float s = a0.x + a0.y + a0.z + a0.w + a1.x + a1.y + a1.z + a1.w;
  float ss = a0.x * a0.x + a0.y * a0.y + a0.z * a0.z + a0.w * a0.w
           + a1.x * a1.x + a1.y * a1.y + a1.z * a1.z + a1.w * a1.w;
#pragma unroll
  for (int d = 1; d < 64; d <<= 1) {
    s += __shfl_xor(s, d, 64);
    ss += __shfl_xor(ss, d, 64);
  }
  const float mean = s * (1.0f / NDIM);
  const float var = ss * (1.0f / NDIM) - mean * mean;
  const float rs = rsqrtf(var + 1e-5f);
  float4 g0 = ((const float4*)g)[lane], g1 = ((const float4*)g)[lane + 64];
  float4 b0 = ((const float4*)b)[lane], b1 = ((const float4*)b)[lane + 64];
  bf16* orow = out + (long long)row * (2 * NDIM);
  float y[8] = {
    (a0.x - mean) * rs * g0.x + b0.x, (a0.y - mean) * rs * g0.y + b0.y,
    (a0.z - mean) * rs * g0.z + b0.z, (a0.w - mean) * rs * g0.w + b0.w,
    (a1.x - mean) * rs * g1.x + b1.x, (a1.y - mean) * rs * g1.y + b1.y,
    (a1.z - mean) * rs * g1.z + b1.z, (a1.w - mean) * rs * g1.w + b1.w };
  bf16x4 h0, h1, l0, l1;
#pragma unroll
  for (int j = 0; j < 4; j++) {
    bf16 h = (bf16)y[j];      h0[j] = h;  l0[j] = (bf16)(y[j] - (float)h);
    bf16 h2 = (bf16)y[4 + j]; h1[j] = h2; l1[j] = (bf16)(y[4 + j] - (float)h2);
  }
  *(bf16x4*)(orow + lane * 4) = h0;
  *(bf16x4*)(orow + 256 + lane * 4) = h1;
  *(bf16x4*)(orow + 512 + lane * 4) = l0;
  *(bf16x4*)(orow + 768 + lane * 4) = l1;
}

// ---------------------------------------------------------------------------
// Ks edge rows: j<16 from mem_k (split), j in [2064,2176) zero. Both batches.
// ---------------------------------------------------------------------------
__global__ __launch_bounds__(256)
void ks_edges(const float* __restrict__ mem_k_l, bf16* __restrict__ Ks)
{
  const int idx = blockIdx.x * 256 + threadIdx.x;  // 2 * 128 * 512
  const int c = idx & 511;
  const int jj = (idx >> 9) & 127;
  const int bb = idx >> 16;
  const int j = (jj < NMEM) ? jj : (jj - NMEM + NJ);
  float kval = 0.f;
  if (jj < NMEM) kval = mem_k_l[((c >> 6) * NMEM + jj) * DHEAD + (c & 63)];
  bf16 hv = (bf16)kval;
  const long long ro = ((long long)bb * NJP + j) * (2 * NDIM) + c;
  Ks[ro] = hv;
  Ks[ro + NDIM] = (bf16)(kval - (float)hv);
}

// ---------------------------------------------------------------------------
// Fused talking-heads mix + bias + top-8 + softmax + sparse PV gather.
// t-group OUTER, h inner, __syncthreads per t-group (lockstep -> L1 reuse).
// Selection via sort4 + bitonic top-8 merge (exact).
// ---------------------------------------------------------------------------
__global__ __launch_bounds__(512)
void mix_topk_gather(const float* __restrict__ S, const float* __restrict__ kvV,
                     const float* __restrict__ mem_v_l, const float* __restrict__ pp,
                     const float* __restrict__ table2, bf16* __restrict__ obufs,
                     int b)
{
  const int i = blockIdx.x;
  const int k = threadIdx.x >> 6;
  const int lane = threadIdx.x & 63;
  const float* srow = S + (long long)i * (NHEADS * NJP);

  float pk[8];
#pragma unroll
  for (int h = 0; h < 8; h++) pk[h] = pp[h * 8 + k];
  const float* t2k = table2 + k * TBL + (2047 - i);

  float v[34];
  float t8[8];
#pragma unroll
  for (int m = 0; m < 8; m++) t8[m] = -3.0e38f;

#define CXP(a, bq) { const float hi = fmaxf(a, bq); const float lo = fminf(a, bq); a = hi; bq = lo; }
#define CXT(a, bq) { const float hi = fmaxf(t8[a], t8[bq]); const float lo = fminf(t8[a], t8[bq]); t8[a] = hi; t8[bq] = lo; }

#pragma unroll
  for (int t = 0; t < 8; t++) {
    const int j0 = 256 * t + 4 * lane;
    float4 a;
    a.x = t2k[j0];
    a.y = t2k[j0 + 1];
    a.z = t2k[j0 + 2];
    a.w = t2k[j0 + 3];
#pragma unroll
    for (int h = 0; h < 8; h++) {
      const float4 s4 = *(const float4*)(srow + h * NJP + j0);
      a.x = fmaf(s4.x, pk[h], a.x);
      a.y = fmaf(s4.y, pk[h], a.y);
      a.z = fmaf(s4.z, pk[h], a.z);
      a.w = fmaf(s4.w, pk[h], a.w);
    }
    v[4 * t + 0] = a.x; v[4 * t + 1] = a.y; v[4 * t + 2] = a.z; v[4 * t + 3] = a.w;
    // sort4 descending (5 CX)
    float s0 = a.x, s1 = a.y, s2 = a.z, s3 = a.w;
    CXP(s0, s1) CXP(s2, s3) CXP(s0, s2) CXP(s1, s3) CXP(s1, s2)
    // bitonic top-8 merge: z[m]=max(t8[m], rev-pad), then 3-stage clean
    t8[4] = fmaxf(t8[4], s3);
    t8[5] = fmaxf(t8[5], s2);
    t8[6] = fmaxf(t8[6], s1);
    t8[7] = fmaxf(t8[7], s0);
    CXT(0, 4) CXT(1, 5) CXT(2, 6) CXT(3, 7)
    CXT(0, 2) CXT(1, 3) CXT(4, 6) CXT(5, 7)
    CXT(0, 1) CXT(2, 3) CXT(4, 5) CXT(6, 7)
    __syncthreads();   // lockstep -> L1 serves duplicate reads
  }
  // tail: 2 elems, sort2 + merge
  {
    const int j0 = 2048 + 2 * lane;
    const int jc = j0 < 2062 ? j0 : 2062;
    float ax = t2k[jc], ay = t2k[jc + 1];
#pragma unroll
    for (int h = 0; h < 8; h++) {
      const float2 s2v = *(const float2*)(srow + h * NJP + j0);
      ax = fmaf(s2v.x, pk[h], ax);
      ay = fmaf(s2v.y, pk[h], ay);
    }
    if (j0 >= NJ) ax = -1e30f;
    if (j0 + 1 >= NJ) ay = -1e30f;
    v[32] = ax; v[33] = ay;
    float s0 = ax, s1 = ay;
    CXP(s0, s1)
    t8[6] = fmaxf(t8[6], s1);
    t8[7] = fmaxf(t8[7], s0);
    CXT(0, 4) CXT(1, 5) CXT(2, 6) CXT(3, 7)
    CXT(0, 2) CXT(1, 3) CXT(4, 6) CXT(5, 7)
    CXT(0, 1) CXT(2, 3) CXT(4, 5) CXT(6, 7)
  }

  // values-only butterfly: global top-8 (sorted desc) in every lane
#pragma unroll
  for (int d = 1; d < 64; d <<= 1) {
    float o[8];
#pragma unroll
    for (int m = 0; m < 8; m++) o[m] = __shfl_xor(t8[m], d, 64);
#pragma unroll
    for (int m = 0; m < 4; m++) t8[m] = fmaxf(t8[m], o[7 - m]);
    t8[4] = fmaxf(t8[4], o[3]); t8[5] = fmaxf(t8[5], o[2]);
    t8[6] = fmaxf(t8[6], o[1]); t8[7] = fmaxf(t8[7], o[0]);
    CXT(0, 4) CXT(1, 5) CXT(2, 6) CXT(3, 7)
    CXT(0, 2) CXT(1, 3) CXT(4, 6) CXT(5, 7)
    CXT(0, 1) CXT(2, 3) CXT(4, 5) CXT(6, 7)
  }
#undef CXT
#undef CXP
  const float mx = t8[0];
  const float thr = t8[7];
  float denom = 0.f;
#pragma unroll
  for (int m = 0; m < 8; m++) denom += __expf(t8[m] - mx);
  const float inv = 1.0f / denom;

  float acc = 0.f;
#pragma unroll
  for (int t = 0; t < 8; t++) {
#pragma unroll
    for (int e = 0; e < 4; e++) {
      unsigned long long mball = __ballot(v[t * 4 + e] >= thr);
      while (mball) {
        const int l = __builtin_ctzll(mball);
        mball &= mball - 1;
        const int jj = 256 * t + 4 * l + e;
        const float sv = __shfl(v[t * 4 + e], l);
        const float w = __expf(sv - mx) * inv;
        const float vv = (jj < NMEM)
            ? mem_v_l[(k * NMEM + jj) * DHEAD + lane]
            : kvV[(long long)(b * NSEQ + (jj - NMEM)) * NDIM + k * DHEAD + lane];
        acc = fmaf(w, vv, acc);
      }
    }
  }
#pragma unroll
  for (int e = 0; e < 2; e++) {
    unsigned long long mball = __ballot(v[32 + e] >= thr);
    while (mball) {
      const int l = __builtin_ctzll(mball);
      mball &= mball - 1;
      const int jj = 2048 + 2 * l + e;
      const float sv = __shfl(v[32 + e], l);
      const float w = __expf(sv - mx) * inv;
      const float vv = (jj < NMEM)
          ? mem_v_l[(k * NMEM + jj) * DHEAD + lane]
          : kvV[(long long)(b * NSEQ + (jj - NMEM)) * NDIM + k * DHEAD + lane];
      acc = fmaf(w, vv, acc);
    }
  }

  const long long orow = (long long)(b * NSEQ + i) * (2 * NDIM) + k * DHEAD + lane;
  bf16 h = (bf16)acc;
  obufs[orow] = h;
  obufs[orow + NDIM] = (bf16)(acc - (float)h);
}

// ---------------------------------------------------------------------------
// fp32 weight (R x C row-major) -> split-transposed bf16 (C x 2R)
// ---------------------------------------------------------------------------
__global__ __launch_bounds__(256)
void transpose_split(const float* __restrict__ in, bf16* __restrict__ out,
                     int R, int C)
{
  const long long idx = (long long)blockIdx.x * 256 + threadIdx.x;
  if (idx >= (long long)R * C) return;
  const int r = (int)(idx / C);
  const int c = (int)(idx % C);
  float v = in[idx];
  bf16 h = (bf16)v;
  out[(long long)c * (2 * R) + r] = h;
  out[(long long)c * (2 * R) + R + r] = (bf16)(v - (float)h);
}

// ---------------------------------------------------------------------------
// T5 bias table, TRANSPOSED: table2[k][rel+2047]; exact boundaries via log2
// ---------------------------------------------------------------------------
__global__ __launch_bounds__(256)
void build_bias2(const float* __restrict__ rel_emb, float* __restrict__ table2)
{
  const int idx = blockIdx.x * 256 + threadIdx.x;
  if (idx >= 8 * TBL) return;
  const int k = idx / TBL;
  const int rel = (idx % TBL) - 2047;
  const int n = -rel;
  const int ret = (n < 0) ? 16 : 0;
  const int na = n < 0 ? -n : n;
  int bucket;
  if (na < 8) {
    bucket = ret + na;
  } else {
    int vl = 8 + (int)(log2((double)na * 0.125) * 2.0);
    vl = vl < 15 ? vl : 15;
    bucket = ret + vl;
  }
  table2[idx] = rel_emb[bucket * 8 + k];
}

// ---------------------------------------------------------------------------
extern "C" void kernel_launch(void* const* d_in, const int* in_sizes, int n_in,
                              void* d_out, int out_size, void* d_ws, size_t ws_size,
                              hipStream_t stream)
{
  const float* x_in    = (const float*)d_in[0];
  const float* ln1_g   = (const float*)d_in[1];
  const float* ln1_b   = (const float*)d_in[2];
  const float* Wq      = (const float*)d_in[3];
  const float* Wkv     = (const float*)d_in[4];
  const float* Wo      = (const float*)d_in[5];
  const float* bo      = (const float*)d_in[6];
  const float* pre_proj= (const float*)d_in[7];
  const float* mem_k   = (const float*)d_in[8];
  const float* mem_v   = (const float*)d_in[9];
  const float* ln2_g   = (const float*)d_in[10];
  const float* ln2_b   = (const float*)d_in[11];
  const float* W1      = (const float*)d_in[12];
  const float* b1      = (const float*)d_in[13];
  const float* W2      = (const float*)d_in[14];
  const float* b2      = (const float*)d_in[15];
  const float* rel_emb = (const float*)d_in[16];

  char* p = (char*)d_ws;
  auto alloc = [&](size_t bytes) -> char* {
    char* r = p;
    p += (bytes + 255) & ~(size_t)255;
    return r;
  };

  float* x    = (float*)alloc((size_t)NROWS * NDIM * 4);          // 8.4 MB
  char*  RA   = alloc((size_t)NROWS * 2 * NDIM * 2);              // 8.4 MB: hs | obufs
  bf16*  hs    = (bf16*)RA;
  bf16*  obufs = (bf16*)RA;
  char*  RB   = alloc((size_t)NROWS * 2 * NFF * 2);               // 33.6 MB: (Qs+Ks) | tbufs
  bf16*  Qs    = (bf16*)RB;
  bf16*  Ks    = (bf16*)(RB + (size_t)NROWS * 2 * NDIM * 2);
  bf16*  tbufs = (bf16*)RB;
  float* kvV  = (float*)alloc((size_t)NROWS * NDIM * 4);          // 8.4 MB (V only)
  float* S    = (float*)alloc((size_t)NSEQ * NHEADS * NJP * 4);   // 142.6 MB, [i][h][j]
  bf16*  WqkvT= (bf16*)alloc((size_t)2 * 3 * NDIM * 2 * NDIM * 2);
  bf16*  WoT  = (bf16*)alloc((size_t)2 * NDIM * 2 * NDIM * 2);
  bf16*  W1T  = (bf16*)alloc((size_t)2 * NFF * 2 * NDIM * 2);
  bf16*  W2T  = (bf16*)alloc((size_t)2 * NDIM * 2 * NFF * 2);
  float* table2= (float*)alloc((size_t)8 * TBL * 4);

  // ---- prep ----
  hipMemcpyAsync(x, x_in, (size_t)NROWS * NDIM * 4, hipMemcpyDeviceToDevice, stream);
  build_bias2<<<(8 * TBL + 255) / 256, 256, 0, stream>>>(rel_emb, table2);
  for (int l = 0; l < 2; l++) {
    bf16* WqkvT_l = WqkvT + (size_t)l * 3 * NDIM * 2 * NDIM;
    transpose_split<<<(NDIM * NDIM + 255) / 256, 256, 0, stream>>>(
        Wq + (size_t)l * NDIM * NDIM, WqkvT_l, NDIM, NDIM);
    transpose_split<<<(2 * NDIM * NDIM + 255) / 256, 256, 0, stream>>>(
        Wkv + (size_t)l * NDIM * 2 * NDIM, WqkvT_l + (size_t)NDIM * 2 * NDIM,
        NDIM, 2 * NDIM);
    transpose_split<<<(NDIM * NDIM + 255) / 256, 256, 0, stream>>>(
        Wo + (size_t)l * NDIM * NDIM, WoT + (size_t)l * NDIM * 2 * NDIM, NDIM, NDIM);
    transpose_split<<<(NDIM * NFF + 255) / 256, 256, 0, stream>>>(
        W1 + (size_t)l * NDIM * NFF, W1T + (size_t)l * NFF * 2 * NDIM, NDIM, NFF);
    transpose_split<<<(NFF * NDIM + 255) / 256, 256, 0, stream>>>(
        W2 + (size_t)l * NFF * NDIM, W2T + (size_t)l * NDIM * 2 * NFF, NFF, NDIM);
  }

  // ---- layers ----
  for (int l = 0; l < 2; l++) {
    const bf16* WqkvT_l = WqkvT + (size_t)l * 3 * NDIM * 2 * NDIM;
    const bf16* WoT_l  = WoT + (size_t)l * NDIM * 2 * NDIM;
    const bf16* W1T_l  = W1T + (size_t)l * NFF * 2 * NDIM;
    const bf16* W2T_l  = W2T + (size_t)l * NDIM * 2 * NFF;
    const float* mem_v_l = mem_v + (size_t)l * NHEADS * NMEM * DHEAD;

    ln_kernel<<<NROWS / 4, 256, 0, stream>>>(x, ln1_g + l * NDIM, ln1_b + l * NDIM, hs);
    // merged QKV: 128x64 tiles -> 32x24 = 768 blocks (3/CU)
    gemm_split<128, 64, 2, 2, EPI_QKV><<<dim3(NROWS / 128, 24), 256, 0, stream>>>(
        hs, WqkvT_l, Qs, nullptr, kvV, Ks, NDIM, 2 * NDIM, 2 * NDIM, 0, NDIM, NDIM);
    ks_edges<<<(2 * 128 * 512) / 256, 256, 0, stream>>>(
        mem_k + (size_t)l * NHEADS * NMEM * DHEAD, Ks);

    for (int b = 0; b < NB; b++) {
      s_gemm_direct<<<dim3(NSEQ / 128, NJP / 128, NHEADS), 256, 0, stream>>>(
          Qs + (long long)b * NSEQ * 1024, Ks + (long long)b * NJP * 1024, S);
      mix_topk_gather<<<NSEQ, 512, 0, stream>>>(
          S, kvV, mem_v_l, pre_proj + l * 64, table2, obufs, b);
    }

    // x += obuf @ Wo + bo  (64x64 tiles -> 512 blocks, 2/CU)
    gemm_split<64, 64, 2, 2, EPI_RESID><<<dim3(NROWS / 64, NDIM / 64), 256, 0, stream>>>(
        obufs, WoT_l, x, bo + l * NDIM, nullptr, nullptr,
        NDIM, 2 * NDIM, 2 * NDIM, NDIM, NDIM, NDIM);

    ln_kernel<<<NROWS / 4, 256, 0, stream>>>(x, ln2_g + l * NDIM, ln2_b + l * NDIM, hs);
    gemm_split<128, 128, 2, 2, EPI_GELUSPLIT><<<dim3(NROWS / 128, NFF / 128), 256, 0, stream>>>(
        hs, W1T_l, tbufs, b1 + l * NFF, nullptr, nullptr,
        NDIM, 2 * NDIM, 2 * NDIM, NFF, NDIM, NDIM);
    // x += gelu @ W2 + b2  (64x64 tiles -> 512 blocks, 2/CU)
    gemm_split<64, 64, 2, 2, EPI_RESID><<<dim3(NROWS / 64, NDIM / 64), 256, 0, stream>>>(
        tbufs, W2T_l, x, b2 + l * NDIM, nullptr, nullptr,
        NFF, 2 * NFF, 2 * NFF, NDIM, NFF, NFF);
  }

  hipMemcpyAsync(d_out, x, (size_t)out_size * 4, hipMemcpyDeviceToDevice, stream);
}